// Round 2
// baseline (132.241 us; speedup 1.0000x reference)
//
#include <hip/hip_runtime.h>
#include <hip/hip_bf16.h>

typedef __attribute__((ext_vector_type(8))) short short8;
typedef __attribute__((ext_vector_type(4))) short short4v;
typedef __attribute__((ext_vector_type(4))) float floatx4;

// Static device buffer for P = E @ W1  (V=50000, H=32 -> 6.4 MB).
__device__ float Pbuf[50000 * 32];

__device__ __forceinline__ short tobf16(float f) {
    unsigned u = __builtin_bit_cast(unsigned, f);
    u += 0x7fffu + ((u >> 16) & 1u);   // round-to-nearest-even
    return (short)(u >> 16);
}

// Row stride for LDS tiles: 336 bf16 = 168 dwords == 8 (mod 32).
// ds_read_b128 fragment reads then hit a uniform 8-access/bank pattern
// (start bank = 8*(m%4)+4*quad covers {0,4,...,28} exactly twice) — the
// bandwidth floor for a 1KB LDS read, i.e. conflict-free in practice.
#define APAD 336

// Kernel 1: P[v][h] = sum_d E[v][d] * W1[d][h]   (50000 x 300) @ (300 x 32)
// v2: coalesced staging. A 64-row E tile is CONTIGUOUS in memory, so the
// block loads it as linear floatx4 (1KB/wave/instr), converts to bf16 once,
// stores to LDS; MFMA fragments come from LDS. This replaces the old
// per-lane scattered fragment loads (16 rows x 32B-strided 16B pieces per
// instruction) that saturated the memory pipe on transaction count.
__global__ __launch_bounds__(256) void project_kernel(
        const float* __restrict__ E, const float* __restrict__ W1, int V) {
    __shared__ __align__(16) short atile[64][APAD];  // E tile, bf16
    __shared__ __align__(16) short w1t[32][APAD];    // W1^T [n][k], bf16

    int tid = threadIdx.x;

    // ---- stage W1 -> LDS (transposed [n][k]); k >= 300 zero-padded ----
#pragma unroll 4
    for (int idx = tid; idx < 320 * 32; idx += 256) {
        int k = idx >> 5, n = idx & 31;
        float wv = (k < 300) ? W1[idx] : 0.f;        // W1[k*32+n] == W1[idx]
        w1t[n][k] = tobf16(wv);
    }

    int v0 = blockIdx.x << 6;
    int nrows = min(64, V - v0);

    // zero-pad A cols 300..319 (read by the masked s=9 step)
    for (int idx = tid; idx < 64 * 20; idx += 256) {
        int r = idx / 20, c = 300 + idx % 20;
        atile[r][c] = 0;
    }

    // ---- stage E rows [v0, v0+nrows): pure linear coalesced loads ----
    // chunk ch covers floats [ch*4, ch*4+4) of the linear 64x300 tile;
    // each row is exactly 75 chunks.
    int nchunk = nrows * 75;
    const float* ebase = E + (size_t)v0 * 300;
    int full = nchunk >> 8;          // full 256-thread rounds (18 when nrows=64)
#pragma unroll 4
    for (int rnd = 0; rnd < full; ++rnd) {
        int ch = tid + (rnd << 8);
        floatx4 f = *(const floatx4*)(ebase + (size_t)ch * 4);
        int r  = ch / 75;
        int c4 = ch - r * 75;
        short4v s;
        s[0] = tobf16(f[0]); s[1] = tobf16(f[1]);
        s[2] = tobf16(f[2]); s[3] = tobf16(f[3]);
        *(short4v*)&atile[r][c4 * 4] = s;
    }
    {
        int ch = tid + (full << 8);
        if (ch < nchunk) {
            floatx4 f = *(const floatx4*)(ebase + (size_t)ch * 4);
            int r  = ch / 75;
            int c4 = ch - r * 75;
            short4v s;
            s[0] = tobf16(f[0]); s[1] = tobf16(f[1]);
            s[2] = tobf16(f[2]); s[3] = tobf16(f[3]);
            *(short4v*)&atile[r][c4 * 4] = s;
        }
    }
    __syncthreads();

    // ---- MFMA: each wave owns a 16-row subtile x full K ----
    int w    = tid >> 6;
    int lane = tid & 63;
    int m    = lane & 15;        // A row within subtile / C col
    int quad = lane >> 4;        // 0..3
    int rowbase = w << 4;
    if (rowbase >= nrows) return;

    floatx4 acc0 = {0.f, 0.f, 0.f, 0.f};
    floatx4 acc1 = {0.f, 0.f, 0.f, 0.f};
#pragma unroll
    for (int s = 0; s < 10; ++s) {
        int kc = s * 32 + quad * 8;
        short8 a  = *(const short8*)&atile[rowbase + m][kc];
        short8 b0 = *(const short8*)&w1t[m][kc];
        short8 b1 = *(const short8*)&w1t[16 + m][kc];
        acc0 = __builtin_amdgcn_mfma_f32_16x16x32_bf16(a, b0, acc0, 0, 0, 0);
        acc1 = __builtin_amdgcn_mfma_f32_16x16x32_bf16(a, b1, acc1, 0, 0, 0);
    }

    // C/D layout (verified): col = lane&15, row = quad*4 + reg
#pragma unroll
    for (int r = 0; r < 4; ++r) {
        int row = v0 + rowbase + quad * 4 + r;
        Pbuf[(size_t)row * 32 + m]      = acc0[r];
        Pbuf[(size_t)row * 32 + 16 + m] = acc1[r];
    }
}

// Kernel 2: per batch row b: acc[h] = sum_l P[x[b,l]][h]; then MLP.
// (unchanged from R1 to isolate the project change)
__global__ __launch_bounds__(256) void pool_mlp_kernel(
        const int* __restrict__ x, const int* __restrict__ lengths,
        const float* __restrict__ b1, const float* __restrict__ W2,
        const float* __restrict__ b2, float* __restrict__ out, int L, int C) {
    __shared__ int   xs[512];
    __shared__ float red[4][32];
    int b    = blockIdx.x;
    int w    = threadIdx.x >> 6;
    int lane = threadIdx.x & 63;
    int h    = lane & 31;
    int th   = lane >> 5;    // lanes 0-31 take even token, 32-63 odd token

    const int* xrow = x + (size_t)b * L;
    for (int i = threadIdx.x; i < L; i += 256) xs[i] = xrow[i];
    __syncthreads();

    int Lw    = (L + 3) >> 2;
    int start = w * Lw;
    int end   = min(start + Lw, L);

    float acc = 0.f;
    int t = start;
    for (; t + 8 <= end; t += 8) {
        int i0 = xs[t + th];
        int i1 = xs[t + 2 + th];
        int i2 = xs[t + 4 + th];
        int i3 = xs[t + 6 + th];
        float v0 = Pbuf[(size_t)i0 * 32 + h];
        float v1 = Pbuf[(size_t)i1 * 32 + h];
        float v2 = Pbuf[(size_t)i2 * 32 + h];
        float v3 = Pbuf[(size_t)i3 * 32 + h];
        acc += v0; acc += v1; acc += v2; acc += v3;
    }
    for (; t < end; t += 2) {
        int tt = t + th;
        if (tt < end) acc += Pbuf[(size_t)xs[tt] * 32 + h];
    }
    acc += __shfl_xor(acc, 32, 64);        // combine both token halves (same h)
    if (lane < 32) red[w][h] = acc;
    __syncthreads();

    if (threadIdx.x < 32) {
        float s    = red[0][h] + red[1][h] + red[2][h] + red[3][h];
        float lenf = (float)lengths[b];
        float hv   = fmaxf(s / lenf + b1[h], 0.f);
        for (int c = 0; c < C; ++c) {
            float p = hv * W2[h * C + c];
            p += __shfl_xor(p, 16, 64);
            p += __shfl_xor(p, 8, 64);
            p += __shfl_xor(p, 4, 64);
            p += __shfl_xor(p, 2, 64);
            p += __shfl_xor(p, 1, 64);
            if (threadIdx.x == 0) out[(size_t)b * C + c] = p + b2[c];
        }
    }
}

// Generic fallback (unexpected shapes): correct, not fast. Uses no workspace.
__global__ void naive_dnn(const int* __restrict__ x, const int* __restrict__ len,
                          const float* __restrict__ emb, const float* __restrict__ W1,
                          const float* __restrict__ b1, const float* __restrict__ W2,
                          const float* __restrict__ b2, float* __restrict__ out,
                          int L, int V, int D, int H, int C) {
    __shared__ float srep[2048];
    __shared__ float sh[256];
    int b = blockIdx.x;
    float lenf = (float)len[b];
    for (int d = threadIdx.x; d < D; d += blockDim.x) {
        float acc = 0.f;
        for (int l = 0; l < L; ++l) {
            int idx = x[(size_t)b * L + l];
            acc += emb[(size_t)idx * D + d];
        }
        srep[d] = acc / lenf;
    }
    __syncthreads();
    for (int hh = threadIdx.x; hh < H; hh += blockDim.x) {
        float a = b1[hh];
        for (int d = 0; d < D; ++d) a += srep[d] * W1[(size_t)d * H + hh];
        sh[hh] = fmaxf(a, 0.f);
    }
    __syncthreads();
    for (int c = threadIdx.x; c < C; c += blockDim.x) {
        float a = b2[c];
        for (int hh = 0; hh < H; ++hh) a += sh[hh] * W2[hh * C + c];
        out[(size_t)b * C + c] = a;
    }
}

extern "C" void kernel_launch(void* const* d_in, const int* in_sizes, int n_in,
                              void* d_out, int out_size, void* d_ws, size_t ws_size,
                              hipStream_t stream) {
    const int*   x       = (const int*)d_in[0];
    const int*   lengths = (const int*)d_in[1];
    const float* emb     = (const float*)d_in[2];
    const float* W1      = (const float*)d_in[3];
    const float* b1      = (const float*)d_in[4];
    const float* W2      = (const float*)d_in[5];
    const float* b2      = (const float*)d_in[6];
    float* out = (float*)d_out;

    int B = in_sizes[1];
    int L = in_sizes[0] / B;
    int H = in_sizes[4];
    int C = in_sizes[6];
    int D = in_sizes[3] / H;
    int V = in_sizes[2] / D;

    bool fast = (D == 300) && (H == 32) && (V == 50000) && (L <= 512);
    if (fast) {
        int blocks = (V + 63) >> 6;        // 782: one 64-row tile per block
        project_kernel<<<blocks, 256, 0, stream>>>(emb, W1, V);
        pool_mlp_kernel<<<B, 256, 0, stream>>>(x, lengths, b1, W2, b2, out, L, C);
    } else {
        naive_dnn<<<B, 256, 0, stream>>>(x, lengths, emb, W1, b1, W2, b2, out,
                                         L, V, D, H, C);
    }
}

// Round 3
// 114.847 us; speedup vs baseline: 1.1515x; 1.1515x over previous
//
#include <hip/hip_runtime.h>
#include <hip/hip_bf16.h>

typedef __attribute__((ext_vector_type(8))) short short8;
typedef __attribute__((ext_vector_type(4))) short short4v;
typedef __attribute__((ext_vector_type(4))) float floatx4;

// Static device buffer for P = E @ W1  (V=50000, H=32 -> 6.4 MB).
__device__ float Pbuf[50000 * 32];

__device__ __forceinline__ short tobf16(float f) {
    unsigned u = __builtin_bit_cast(unsigned, f);
    u += 0x7fffu + ((u >> 16) & 1u);   // round-to-nearest-even
    return (short)(u >> 16);
}

// LDS row stride: 336 bf16 = 168 dwords == 8 (mod 32) -> ds_read_b128 MFMA
// fragment reads hit the uniform 8-access/bank floor (conflict-free).
#define APAD 336

// Kernel 1: P[v][h] = sum_d E[v][d] * W1[d][h]   (50000 x 300) @ (300 x 32)
// v3: cross-tile software pipeline (T14 async-STAGE split), 1 block/CU.
//   R1/R2 post-mortem: every phase-serial variant (stage -> barrier ->
//   compute) lands at ~42us with ~0.25 wave-loads in flight per wave —
//   latency-chain bound, not BW bound. This version keeps the NEXT tile's
//   19 global_load_dwordx4 in flight across the CURRENT tile's MFMA+store
//   phase: issue loads -> compute -> drain+convert+ds_write -> one barrier.
//   256 blocks x ~3 tiles each, double-buffered 64-row A tile in LDS.
__global__ __launch_bounds__(256, 1) void project_kernel(
        const float* __restrict__ E, const float* __restrict__ W1, int V) {
    __shared__ __align__(16) short w1t[32][APAD];        // W1^T [n][k], bf16
    __shared__ __align__(16) short atile[2][64][APAD];   // double-buffered E tile

    int tid   = threadIdx.x;
    int b     = blockIdx.x;
    int tiles = (V + 63) >> 6;                 // 782
    int NT    = (tiles - b + 255) >> 8;        // tiles this block: b + 256*i

    // Zero K-pad cols 300..319 once (persist across iterations).
    for (int idx = tid; idx < 2 * 64 * 20; idx += 256) {
        int bufi = idx / (64 * 20);
        int rem  = idx % (64 * 20);
        atile[bufi][rem / 20][300 + rem % 20] = 0;
    }
    for (int idx = tid; idx < 32 * 20; idx += 256)
        w1t[idx / 20][300 + idx % 20] = 0;

    // A-tile staging map (div-free): thread -> (row, q); chunks c = q + 4j.
    int arow = tid >> 2;        // 0..63
    int aq   = tid & 3;

    // ---- prologue: issue W1 + tile-0 loads together, then convert+write ----
    floatx4 wreg[10];
#pragma unroll
    for (int r = 0; r < 10; ++r) {
        int ch = tid + (r << 8);
        if (ch < 2400) wreg[r] = *(const floatx4*)(W1 + (size_t)ch * 4);
    }
    floatx4 areg[19];
    {
        int t0 = b;
        int nrows0 = min(64, V - (t0 << 6));
        const float* eb = E + ((size_t)t0 << 6) * 300;
#pragma unroll
        for (int j = 0; j < 19; ++j) {
            int c = aq + 4 * j;
            if (c < 75 && arow < nrows0)
                areg[j] = *(const floatx4*)(eb + (size_t)arow * 300 + c * 4);
        }
    }
#pragma unroll
    for (int r = 0; r < 10; ++r) {
        int ch = tid + (r << 8);
        if (ch < 2400) {
            int flat = ch * 4;
            int k = flat >> 5, n0 = flat & 31;
#pragma unroll
            for (int jj = 0; jj < 4; ++jj) w1t[n0 + jj][k] = tobf16(wreg[r][jj]);
        }
    }
    {
        int nrows0 = min(64, V - (b << 6));
#pragma unroll
        for (int j = 0; j < 19; ++j) {
            int c = aq + 4 * j;
            if (c < 75 && arow < nrows0) {
                short4v s;
#pragma unroll
                for (int jj = 0; jj < 4; ++jj) s[jj] = tobf16(areg[j][jj]);
                *(short4v*)&atile[0][arow][c * 4] = s;
            }
        }
    }
    __syncthreads();

    int lane = tid & 63;
    int w    = tid >> 6;
    int m    = lane & 15;
    int quad = lane >> 4;
    int rowbase = w << 4;

    for (int i = 0; i < NT; ++i) {
        int t   = b + (i << 8);
        int cur = i & 1;
        bool pf = (i + 1 < NT);
        int tn  = t + 256;
        int nrowsN = pf ? min(64, V - (tn << 6)) : 0;

        // (A) issue next tile's loads — stay in flight through (B)/(C)
        const float* eb2 = E + ((size_t)tn << 6) * 300;
#pragma unroll
        for (int j = 0; j < 19; ++j) {
            int c = aq + 4 * j;
            if (pf && c < 75 && arow < nrowsN)
                areg[j] = *(const floatx4*)(eb2 + (size_t)arow * 300 + c * 4);
        }

        // (B) MFMA on current tile from LDS
        int nrows = min(64, V - (t << 6));
        if (rowbase < nrows) {
            floatx4 acc0 = {0.f, 0.f, 0.f, 0.f};
            floatx4 acc1 = {0.f, 0.f, 0.f, 0.f};
#pragma unroll
            for (int s = 0; s < 10; ++s) {
                int kc = s * 32 + quad * 8;
                short8 a  = *(const short8*)&atile[cur][rowbase + m][kc];
                short8 b0 = *(const short8*)&w1t[m][kc];
                short8 b1 = *(const short8*)&w1t[16 + m][kc];
                acc0 = __builtin_amdgcn_mfma_f32_16x16x32_bf16(a, b0, acc0, 0, 0, 0);
                acc1 = __builtin_amdgcn_mfma_f32_16x16x32_bf16(a, b1, acc1, 0, 0, 0);
            }
            // (C) store P rows (C/D layout: col = lane&15, row = quad*4 + r)
#pragma unroll
            for (int r = 0; r < 4; ++r) {
                int row = (t << 6) + rowbase + quad * 4 + r;
                Pbuf[(size_t)row * 32 + m]      = acc0[r];
                Pbuf[(size_t)row * 32 + 16 + m] = acc1[r];
            }
        }

        // (D) drain loads, convert, write into the other buffer
        if (pf) {
#pragma unroll
            for (int j = 0; j < 19; ++j) {
                int c = aq + 4 * j;
                if (c < 75 && arow < nrowsN) {
                    short4v s;
#pragma unroll
                    for (int jj = 0; jj < 4; ++jj) s[jj] = tobf16(areg[j][jj]);
                    *(short4v*)&atile[cur ^ 1][arow][c * 4] = s;
                }
            }
        }
        // (E) one barrier per tile: protects both buffers' read/write phases
        __syncthreads();
    }
}

// Kernel 2: per batch row b: acc[h] = sum_l P[x[b,l]][h]; then MLP.
// (~9us, near its gather-BW floor — unchanged)
__global__ __launch_bounds__(256) void pool_mlp_kernel(
        const int* __restrict__ x, const int* __restrict__ lengths,
        const float* __restrict__ b1, const float* __restrict__ W2,
        const float* __restrict__ b2, float* __restrict__ out, int L, int C) {
    __shared__ int   xs[512];
    __shared__ float red[4][32];
    int b    = blockIdx.x;
    int w    = threadIdx.x >> 6;
    int lane = threadIdx.x & 63;
    int h    = lane & 31;
    int th   = lane >> 5;

    const int* xrow = x + (size_t)b * L;
    for (int i = threadIdx.x; i < L; i += 256) xs[i] = xrow[i];
    __syncthreads();

    int Lw    = (L + 3) >> 2;
    int start = w * Lw;
    int end   = min(start + Lw, L);

    float acc = 0.f;
    int t = start;
    for (; t + 8 <= end; t += 8) {
        int i0 = xs[t + th];
        int i1 = xs[t + 2 + th];
        int i2 = xs[t + 4 + th];
        int i3 = xs[t + 6 + th];
        float v0 = Pbuf[(size_t)i0 * 32 + h];
        float v1 = Pbuf[(size_t)i1 * 32 + h];
        float v2 = Pbuf[(size_t)i2 * 32 + h];
        float v3 = Pbuf[(size_t)i3 * 32 + h];
        acc += v0; acc += v1; acc += v2; acc += v3;
    }
    for (; t < end; t += 2) {
        int tt = t + th;
        if (tt < end) acc += Pbuf[(size_t)xs[tt] * 32 + h];
    }
    acc += __shfl_xor(acc, 32, 64);
    if (lane < 32) red[w][h] = acc;
    __syncthreads();

    if (threadIdx.x < 32) {
        float s    = red[0][h] + red[1][h] + red[2][h] + red[3][h];
        float lenf = (float)lengths[b];
        float hv   = fmaxf(s / lenf + b1[h], 0.f);
        for (int c = 0; c < C; ++c) {
            float p = hv * W2[h * C + c];
            p += __shfl_xor(p, 16, 64);
            p += __shfl_xor(p, 8, 64);
            p += __shfl_xor(p, 4, 64);
            p += __shfl_xor(p, 2, 64);
            p += __shfl_xor(p, 1, 64);
            if (threadIdx.x == 0) out[(size_t)b * C + c] = p + b2[c];
        }
    }
}

// Generic fallback (unexpected shapes): correct, not fast.
__global__ void naive_dnn(const int* __restrict__ x, const int* __restrict__ len,
                          const float* __restrict__ emb, const float* __restrict__ W1,
                          const float* __restrict__ b1, const float* __restrict__ W2,
                          const float* __restrict__ b2, float* __restrict__ out,
                          int L, int V, int D, int H, int C) {
    __shared__ float srep[2048];
    __shared__ float sh[256];
    int b = blockIdx.x;
    float lenf = (float)len[b];
    for (int d = threadIdx.x; d < D; d += blockDim.x) {
        float acc = 0.f;
        for (int l = 0; l < L; ++l) {
            int idx = x[(size_t)b * L + l];
            acc += emb[(size_t)idx * D + d];
        }
        srep[d] = acc / lenf;
    }
    __syncthreads();
    for (int hh = threadIdx.x; hh < H; hh += blockDim.x) {
        float a = b1[hh];
        for (int d = 0; d < D; ++d) a += srep[d] * W1[(size_t)d * H + hh];
        sh[hh] = fmaxf(a, 0.f);
    }
    __syncthreads();
    for (int c = threadIdx.x; c < C; c += blockDim.x) {
        float a = b2[c];
        for (int hh = 0; hh < H; ++hh) a += sh[hh] * W2[hh * C + c];
        out[(size_t)b * C + c] = a;
    }
}

extern "C" void kernel_launch(void* const* d_in, const int* in_sizes, int n_in,
                              void* d_out, int out_size, void* d_ws, size_t ws_size,
                              hipStream_t stream) {
    const int*   x       = (const int*)d_in[0];
    const int*   lengths = (const int*)d_in[1];
    const float* emb     = (const float*)d_in[2];
    const float* W1      = (const float*)d_in[3];
    const float* b1      = (const float*)d_in[4];
    const float* W2      = (const float*)d_in[5];
    const float* b2      = (const float*)d_in[6];
    float* out = (float*)d_out;

    int B = in_sizes[1];
    int L = in_sizes[0] / B;
    int H = in_sizes[4];
    int C = in_sizes[6];
    int D = in_sizes[3] / H;
    int V = in_sizes[2] / D;

    bool fast = (D == 300) && (H == 32) && (V == 50000) && (L <= 512);
    if (fast) {
        int tiles  = (V + 63) >> 6;            // 782
        int blocks = min(256, tiles);          // 1 block/CU, ~3 tiles each
        project_kernel<<<blocks, 256, 0, stream>>>(emb, W1, V);
        pool_mlp_kernel<<<B, 256, 0, stream>>>(x, lengths, b1, W2, b2, out, L, C);
    } else {
        naive_dnn<<<B, 256, 0, stream>>>(x, lengths, emb, W1, b1, W2, b2, out,
                                         L, V, D, H, C);
    }
}

// Round 4
// 112.742 us; speedup vs baseline: 1.1730x; 1.0187x over previous
//
#include <hip/hip_runtime.h>
#include <hip/hip_bf16.h>

typedef __attribute__((ext_vector_type(8))) short short8;
typedef __attribute__((ext_vector_type(4))) short short4v;
typedef __attribute__((ext_vector_type(4))) float floatx4;

// Static device buffer for P = E @ W1  (V=50000, H=32 -> 6.4 MB).
__device__ float Pbuf[50000 * 32];

__device__ __forceinline__ short tobf16(float f) {
    unsigned u = __builtin_bit_cast(unsigned, f);
    u += 0x7fffu + ((u >> 16) & 1u);   // round-to-nearest-even
    return (short)(u >> 16);
}

// LDS row stride: 336 bf16 = 168 dwords == 8 (mod 32) -> ds_read_b128 MFMA
// fragment reads hit the uniform 8-access/bank floor (conflict-free).
#define APAD 336

// Kernel 1: P[v][h] = sum_d E[v][d] * W1[d][h]   (50000 x 300) @ (300 x 32)
// v4: 32-row tiles, 2 blocks/CU (cross-block overlap hides each block's
// barrier/drain bubbles), wave-pair N-split (w0/w1: cols 0-15, w2/w3:
// cols 16-31 -> no LDS reduce), W1 B-frags register-resident, prefetch
// issue pinned above MFMA with sched_barrier(0), P-stores after ds_writes
// so the drain vmcnt covers loads only.
//   R3 post-mortem: 1 block/CU + 64-row tiles = 27us; 14/256 blocks ran a
//   4th tile (33% tail) and every barrier stalled the whole CU.
__global__ __launch_bounds__(256, 2) void project_kernel(
        const float* __restrict__ E, const float* __restrict__ W1, int V) {
    __shared__ __align__(16) short w1t[32][APAD];        // W1^T [n][k], bf16
    __shared__ __align__(16) short atile[2][32][APAD];   // double-buffered E tile

    int tid   = threadIdx.x;
    int b     = blockIdx.x;
    int tiles = (V + 31) >> 5;                 // 1563
    int NT    = (tiles - b + 511) >> 9;        // tiles this block: b + 512*i

    // Zero K-pad cols 300..319 once (persist across iterations).
    for (int idx = tid; idx < 2 * 32 * 20; idx += 256) {
        int bufi = idx / (32 * 20);
        int rem  = idx % (32 * 20);
        atile[bufi][rem / 20][300 + rem % 20] = 0;
    }
    for (int idx = tid; idx < 32 * 20; idx += 256)
        w1t[idx / 20][300 + idx % 20] = 0;

    // A-tile staging map (div-free): thread -> (row, q); chunks c = q + 8j.
    int arow = tid >> 3;        // 0..31
    int aq   = tid & 7;         // 0..7

    // ---- prologue: issue W1 + tile-0 loads together, then convert+write ----
    floatx4 wreg[10];
#pragma unroll
    for (int r = 0; r < 10; ++r) {
        int ch = tid + (r << 8);
        if (ch < 2400) wreg[r] = *(const floatx4*)(W1 + (size_t)ch * 4);
    }
    floatx4 areg[10];
    {
        int nrows0 = min(32, V - (b << 5));
        const float* eb = E + ((size_t)b << 5) * 300;
#pragma unroll
        for (int j = 0; j < 10; ++j) {
            int c = aq + 8 * j;
            if (c < 75 && arow < nrows0)
                areg[j] = *(const floatx4*)(eb + (size_t)arow * 300 + c * 4);
        }
    }
#pragma unroll
    for (int r = 0; r < 10; ++r) {
        int ch = tid + (r << 8);
        if (ch < 2400) {
            int flat = ch * 4;
            int k = flat >> 5, n0 = flat & 31;
#pragma unroll
            for (int jj = 0; jj < 4; ++jj) w1t[n0 + jj][k] = tobf16(wreg[r][jj]);
        }
    }
    {
        int nrows0 = min(32, V - (b << 5));
#pragma unroll
        for (int j = 0; j < 10; ++j) {
            int c = aq + 8 * j;
            if (c < 75 && arow < nrows0) {
                short4v s;
#pragma unroll
                for (int jj = 0; jj < 4; ++jj) s[jj] = tobf16(areg[j][jj]);
                *(short4v*)&atile[0][arow][c * 4] = s;
            }
        }
    }
    __syncthreads();

    int lane   = tid & 63;
    int w      = tid >> 6;
    int m      = lane & 15;
    int quad   = lane >> 4;
    int rowsub = (w & 1) << 4;       // 0 or 16: row subtile
    int ncol0  = (w >> 1) << 4;      // 0 or 16: output-column half

    // W1 B-frags are tile-invariant: hoist to registers (kills 1/2 of the
    // per-tile LDS reads; w1t not read again after this).
    short8 bfrag[10];
#pragma unroll
    for (int s = 0; s < 10; ++s)
        bfrag[s] = *(const short8*)&w1t[ncol0 + m][s * 32 + quad * 8];

    for (int i = 0; i < NT; ++i) {
        int t   = b + (i << 9);
        int cur = i & 1;
        bool pf = (i + 1 < NT);
        int tn  = t + 512;
        int nrowsN = pf ? min(32, V - (tn << 5)) : 0;

        // (A) issue next tile's loads — stay in flight through (B)
        const float* eb2 = E + ((size_t)tn << 5) * 300;
#pragma unroll
        for (int j = 0; j < 10; ++j) {
            int c = aq + 8 * j;
            if (pf && c < 75 && arow < nrowsN)
                areg[j] = *(const floatx4*)(eb2 + (size_t)arow * 300 + c * 4);
        }
        __builtin_amdgcn_sched_barrier(0);   // pin load issue above MFMA

        // (B) MFMA on current tile from LDS
        int nrows = min(32, V - (t << 5));
        floatx4 acc = {0.f, 0.f, 0.f, 0.f};
        if (rowsub < nrows) {
#pragma unroll
            for (int s = 0; s < 10; ++s) {
                short8 a = *(const short8*)&atile[cur][rowsub + m][s * 32 + quad * 8];
                acc = __builtin_amdgcn_mfma_f32_16x16x32_bf16(a, bfrag[s], acc, 0, 0, 0);
            }
        }

        // (C) drain loads, convert, write into the other buffer
        if (pf) {
#pragma unroll
            for (int j = 0; j < 10; ++j) {
                int c = aq + 8 * j;
                if (c < 75 && arow < nrowsN) {
                    short4v s;
#pragma unroll
                    for (int jj = 0; jj < 4; ++jj) s[jj] = tobf16(areg[j][jj]);
                    *(short4v*)&atile[cur ^ 1][arow][c * 4] = s;
                }
            }
        }

        // (D) store P rows (after ds_writes: stores fly during the barrier;
        //     C/D layout: col = lane&15, row = quad*4 + r)
        if (rowsub < nrows) {
#pragma unroll
            for (int r = 0; r < 4; ++r) {
                int row = (t << 5) + rowsub + quad * 4 + r;
                Pbuf[(size_t)row * 32 + ncol0 + m] = acc[r];
            }
        }

        // (E) one barrier per tile
        __syncthreads();
    }
}

// Kernel 2: per batch row b: acc[h] = sum_l P[x[b,l]][h]; then MLP.
// (~7us — unchanged)
__global__ __launch_bounds__(256) void pool_mlp_kernel(
        const int* __restrict__ x, const int* __restrict__ lengths,
        const float* __restrict__ b1, const float* __restrict__ W2,
        const float* __restrict__ b2, float* __restrict__ out, int L, int C) {
    __shared__ int   xs[512];
    __shared__ float red[4][32];
    int b    = blockIdx.x;
    int w    = threadIdx.x >> 6;
    int lane = threadIdx.x & 63;
    int h    = lane & 31;
    int th   = lane >> 5;

    const int* xrow = x + (size_t)b * L;
    for (int i = threadIdx.x; i < L; i += 256) xs[i] = xrow[i];
    __syncthreads();

    int Lw    = (L + 3) >> 2;
    int start = w * Lw;
    int end   = min(start + Lw, L);

    float acc = 0.f;
    int t = start;
    for (; t + 8 <= end; t += 8) {
        int i0 = xs[t + th];
        int i1 = xs[t + 2 + th];
        int i2 = xs[t + 4 + th];
        int i3 = xs[t + 6 + th];
        float v0 = Pbuf[(size_t)i0 * 32 + h];
        float v1 = Pbuf[(size_t)i1 * 32 + h];
        float v2 = Pbuf[(size_t)i2 * 32 + h];
        float v3 = Pbuf[(size_t)i3 * 32 + h];
        acc += v0; acc += v1; acc += v2; acc += v3;
    }
    for (; t < end; t += 2) {
        int tt = t + th;
        if (tt < end) acc += Pbuf[(size_t)xs[tt] * 32 + h];
    }
    acc += __shfl_xor(acc, 32, 64);
    if (lane < 32) red[w][h] = acc;
    __syncthreads();

    if (threadIdx.x < 32) {
        float s    = red[0][h] + red[1][h] + red[2][h] + red[3][h];
        float lenf = (float)lengths[b];
        float hv   = fmaxf(s / lenf + b1[h], 0.f);
        for (int c = 0; c < C; ++c) {
            float p = hv * W2[h * C + c];
            p += __shfl_xor(p, 16, 64);
            p += __shfl_xor(p, 8, 64);
            p += __shfl_xor(p, 4, 64);
            p += __shfl_xor(p, 2, 64);
            p += __shfl_xor(p, 1, 64);
            if (threadIdx.x == 0) out[(size_t)b * C + c] = p + b2[c];
        }
    }
}

// Generic fallback (unexpected shapes): correct, not fast.
__global__ void naive_dnn(const int* __restrict__ x, const int* __restrict__ len,
                          const float* __restrict__ emb, const float* __restrict__ W1,
                          const float* __restrict__ b1, const float* __restrict__ W2,
                          const float* __restrict__ b2, float* __restrict__ out,
                          int L, int V, int D, int H, int C) {
    __shared__ float srep[2048];
    __shared__ float sh[256];
    int b = blockIdx.x;
    float lenf = (float)len[b];
    for (int d = threadIdx.x; d < D; d += blockDim.x) {
        float acc = 0.f;
        for (int l = 0; l < L; ++l) {
            int idx = x[(size_t)b * L + l];
            acc += emb[(size_t)idx * D + d];
        }
        srep[d] = acc / lenf;
    }
    __syncthreads();
    for (int hh = threadIdx.x; hh < H; hh += blockDim.x) {
        float a = b1[hh];
        for (int d = 0; d < D; ++d) a += srep[d] * W1[(size_t)d * H + hh];
        sh[hh] = fmaxf(a, 0.f);
    }
    __syncthreads();
    for (int c = threadIdx.x; c < C; c += blockDim.x) {
        float a = b2[c];
        for (int hh = 0; hh < H; ++hh) a += sh[hh] * W2[hh * C + c];
        out[(size_t)b * C + c] = a;
    }
}

extern "C" void kernel_launch(void* const* d_in, const int* in_sizes, int n_in,
                              void* d_out, int out_size, void* d_ws, size_t ws_size,
                              hipStream_t stream) {
    const int*   x       = (const int*)d_in[0];
    const int*   lengths = (const int*)d_in[1];
    const float* emb     = (const float*)d_in[2];
    const float* W1      = (const float*)d_in[3];
    const float* b1      = (const float*)d_in[4];
    const float* W2      = (const float*)d_in[5];
    const float* b2      = (const float*)d_in[6];
    float* out = (float*)d_out;

    int B = in_sizes[1];
    int L = in_sizes[0] / B;
    int H = in_sizes[4];
    int C = in_sizes[6];
    int D = in_sizes[3] / H;
    int V = in_sizes[2] / D;

    bool fast = (D == 300) && (H == 32) && (V == 50000) && (L <= 512);
    if (fast) {
        int tiles  = (V + 31) >> 5;            // 1563
        int blocks = min(512, tiles);          // 2 blocks/CU, ~3 tiles each
        project_kernel<<<blocks, 256, 0, stream>>>(emb, W1, V);
        pool_mlp_kernel<<<B, 256, 0, stream>>>(x, lengths, b1, W2, b2, out, L, C);
    } else {
        naive_dnn<<<B, 256, 0, stream>>>(x, lengths, emb, W1, b1, W2, b2, out,
                                         L, V, D, H, C);
    }
}